// Round 5
// baseline (131.073 us; speedup 1.0000x reference)
//
#include <hip/hip_runtime.h>

// steps = 65536, channels = 6, state = [pos(6), vel(6)]
// Closed form of the scan:
//   S_t = sum_{i<=t} a_i        (per channel)
//   W_t = sum_{i<=t} i * a_i    (per channel)
//   vel[t] = v0 + dt*S_t
//   pos[t] = p0 + dt*(t+1)*v0 + dt^2*((t+0.5)*S_t - W_t)
// Output layout: states [65536,12] flat, then actions [65536,6] flat.
//
// SINGLE kernel with decoupled lookback: each block publishes its per-channel
// (S,W) aggregate to d_ws + a release flag, then sums all predecessors'
// aggregates (agent-scope atomic loads, spin on flag). 256 blocks = 1/CU, all
// co-resident; publishing never waits -> no deadlock. Harness poisons d_ws to
// 0xAA before every launch, so flag==0xAAAAAAAA means "not ready" (and since
// inputs are deterministic, even a stale TAG guards byte-identical values).
// All global IO is coalesced float4 via LDS staging.

#define STEPS   65536
#define NCH     6
#define STATE   12
#define NB      256
#define CHUNK   (STEPS / NB)        // 256 steps per block
#define BLK     (NCH * 64)          // 384 threads = 6 waves; wave w <-> channel w
#define ACT_OFF (STEPS * STATE)     // float offset of actions region in out
#define TAG     0x5AF0C0DEu

__global__ __launch_bounds__(BLK) void k_one(const float4* __restrict__ act4,
                                             const float* __restrict__ x,
                                             double* __restrict__ agg,
                                             unsigned int* __restrict__ flags,
                                             float4* __restrict__ out4) {
    __shared__ float sIn[CHUNK * NCH];          // 6 KiB
    __shared__ float sOut[CHUNK * STATE];       // 12 KiB
    const int b = blockIdx.x, tid = threadIdx.x;
    const int c = tid >> 6, lane = tid & 63;

    // ---- Phase A: stage-in (coalesced) + actions passthrough.
    float4 v = act4[b * (CHUNK * NCH / 4) + tid];
    ((float4*)sIn)[tid] = v;
    out4[ACT_OFF / 4 + b * (CHUNK * NCH / 4) + tid] = v;
    __syncthreads();

    // ---- Phase B: block-local (S,W) aggregate for channel c; publish.
    double sA = 0.0, sW = 0.0;
#pragma unroll
    for (int k = 0; k < CHUNK / 64; ++k) {
        const int   tl = k * 64 + lane;
        const float a  = sIn[tl * NCH + c];
        sA += (double)a;
        sW += (double)(b * CHUNK + tl) * (double)a;
    }
#pragma unroll
    for (int off = 32; off > 0; off >>= 1) {
        sA += __shfl_down(sA, off, 64);
        sW += __shfl_down(sW, off, 64);
    }
    if (lane == 0) {
        agg[(b * NCH + c) * 2 + 0] = sA;
        agg[(b * NCH + c) * 2 + 1] = sW;
        __threadfence();    // push this wave's payload to device-coherent point
    }
    __syncthreads();
    if (tid == 0)
        __hip_atomic_store(&flags[b], TAG, __ATOMIC_RELEASE,
                           __HIP_MEMORY_SCOPE_AGENT);

    // ---- Phase C: lookback — wave c sums predecessors' channel-c aggregates.
    double vA = 0.0, vW = 0.0;
    for (int p = lane; p < b; p += 64) {
        while (__hip_atomic_load(&flags[p], __ATOMIC_ACQUIRE,
                                 __HIP_MEMORY_SCOPE_AGENT) != TAG)
            __builtin_amdgcn_s_sleep(1);
        vA += __hip_atomic_load(&agg[(p * NCH + c) * 2 + 0], __ATOMIC_RELAXED,
                                __HIP_MEMORY_SCOPE_AGENT);
        vW += __hip_atomic_load(&agg[(p * NCH + c) * 2 + 1], __ATOMIC_RELAXED,
                                __HIP_MEMORY_SCOPE_AGENT);
    }
#pragma unroll
    for (int off = 32; off > 0; off >>= 1) {
        vA += __shfl_down(vA, off, 64);
        vW += __shfl_down(vW, off, 64);
    }
    double accA = __shfl(vA, 0, 64);
    double accW = __shfl(vW, 0, 64);

    const double dt  = (double)0.1f;   // match float32(0.1) bit pattern
    const double dt2 = dt * dt;
    const double p0  = (double)x[c];
    const double v0  = (double)x[NCH + c];

    // ---- Phase D: in-chunk scan, 4 sequential 64-step wave-scans.
#pragma unroll
    for (int k = 0; k < CHUNK / 64; ++k) {
        const int   tl = k * 64 + lane;
        const int   t  = b * CHUNK + tl;
        const float a  = sIn[tl * NCH + c];
        double iA = (double)a;
        double iW = (double)t * (double)a;
#pragma unroll
        for (int off = 1; off < 64; off <<= 1) {
            const double uA = __shfl_up(iA, off, 64);
            const double uW = __shfl_up(iW, off, 64);
            if (lane >= off) { iA += uA; iW += uW; }
        }
        const double runA = accA + iA;
        const double runW = accW + iW;
        const double vel = v0 + dt * runA;
        const double pos = p0 + dt * (double)(t + 1) * v0
                         + dt2 * (((double)t + 0.5) * runA - runW);
        sOut[tl * STATE + c]       = (float)pos;
        sOut[tl * STATE + NCH + c] = (float)vel;
        accA += __shfl(iA, 63, 64);
        accW += __shfl(iW, 63, 64);
    }
    __syncthreads();

    // ---- Phase E: coalesced writeout of the CHUNK x 12 state chunk.
    const float4* so4 = (const float4*)sOut;
    out4[b * (CHUNK * STATE / 4) + tid]       = so4[tid];
    out4[b * (CHUNK * STATE / 4) + BLK + tid] = so4[BLK + tid];
}

extern "C" void kernel_launch(void* const* d_in, const int* in_sizes, int n_in,
                              void* d_out, int out_size, void* d_ws, size_t ws_size,
                              hipStream_t stream) {
    const float* x       = (const float*)d_in[0];   // 12 floats: pos(6), vel(6)
    const float* actions = (const float*)d_in[1];   // [65536, 6]
    float*       out     = (float*)d_out;           // states(786432) + actions(393216)

    double*       agg   = (double*)d_ws;                      // NB*NCH*2 = 24 KiB
    unsigned int* flags = (unsigned int*)((char*)d_ws + NB * NCH * 2 * sizeof(double));

    hipLaunchKernelGGL(k_one, dim3(NB), dim3(BLK), 0, stream,
                       (const float4*)actions, x, agg, flags, (float4*)out);
}

// Round 6
// 65.130 us; speedup vs baseline: 2.0125x; 2.0125x over previous
//
#include <hip/hip_runtime.h>

// steps = 65536, channels = 6, state = [pos(6), vel(6)]
// Closed form of the scan:
//   S_t = sum_{i<=t} a_i        (per channel)
//   W_t = sum_{i<=t} i * a_i    (per channel)
//   vel[t] = v0 + dt*S_t
//   pos[t] = p0 + dt*(t+1)*v0 + dt^2*((t+0.5)*S_t - W_t)
// Output layout: states [65536,12] flat, then actions [65536,6] flat.
//
// SINGLE kernel, decoupled lookback with NO fences/flags: per-block (S,W)
// aggregates are published as relaxed 64-bit agent-scope atomic stores
// (atomics operate at the device-coherent point -> no buffer_wbl2 L2
// writeback, which is what killed the R5 release/acquire version on this
// multi-XCD part). Each payload word is self-validating: the harness poisons
// d_ws to 0xAA before every launch, and 0xAAAAAAAAAAAAAAAA as a double
// (~ -3.5e-103) is unreachable by sums of unit normals, so "word != poison"
// == "word ready". Publish happens before any wait -> deadlock-free (and
// 256 blocks = 1/CU are co-resident regardless). All global IO is coalesced
// float4 via LDS staging.

#define STEPS   65536
#define NCH     6
#define STATE   12
#define NB      256
#define CHUNK   (STEPS / NB)        // 256 steps per block
#define BLK     (NCH * 64)          // 384 threads = 6 waves; wave w <-> channel w
#define ACT_OFF (STEPS * STATE)     // float offset of actions region in out
#define POISON  0xAAAAAAAAAAAAAAAAull

__device__ __forceinline__ void agg_pub(unsigned long long* p, double v) {
    __hip_atomic_store(p, (unsigned long long)__double_as_longlong(v),
                       __ATOMIC_RELAXED, __HIP_MEMORY_SCOPE_AGENT);
}

__device__ __forceinline__ double agg_wait(const unsigned long long* p) {
    unsigned long long u = __hip_atomic_load(p, __ATOMIC_RELAXED,
                                             __HIP_MEMORY_SCOPE_AGENT);
    while (u == POISON) {
        __builtin_amdgcn_s_sleep(1);
        u = __hip_atomic_load(p, __ATOMIC_RELAXED, __HIP_MEMORY_SCOPE_AGENT);
    }
    return __longlong_as_double((long long)u);
}

__global__ __launch_bounds__(BLK) void k_one(const float4* __restrict__ act4,
                                             const float* __restrict__ x,
                                             unsigned long long* __restrict__ agg,
                                             float4* __restrict__ out4) {
    __shared__ float sIn[CHUNK * NCH];          // 6 KiB
    __shared__ float sOut[CHUNK * STATE];       // 12 KiB
    const int b = blockIdx.x, tid = threadIdx.x;
    const int c = tid >> 6, lane = tid & 63;

    // ---- Phase A: stage-in (coalesced). Actions-copy store deferred to
    // after publish so aggregates land at the coherent point ASAP.
    const float4 v = act4[b * (CHUNK * NCH / 4) + tid];
    ((float4*)sIn)[tid] = v;
    __syncthreads();

    // ---- Phase B: block-local (S,W) aggregate for channel c; publish.
    {
        double sA = 0.0, sW = 0.0;
#pragma unroll
        for (int k = 0; k < CHUNK / 64; ++k) {
            const int   tl = k * 64 + lane;
            const float a  = sIn[tl * NCH + c];
            sA += (double)a;
            sW += (double)(b * CHUNK + tl) * (double)a;
        }
#pragma unroll
        for (int off = 32; off > 0; off >>= 1) {
            sA += __shfl_down(sA, off, 64);
            sW += __shfl_down(sW, off, 64);
        }
        if (lane == 0) {
            agg_pub(&agg[(b * NCH + c) * 2 + 0], sA);
            agg_pub(&agg[(b * NCH + c) * 2 + 1], sW);
        }
    }

    // Actions passthrough (coalesced float4), overlaps others' publishes.
    out4[ACT_OFF / 4 + b * (CHUNK * NCH / 4) + tid] = v;

    // ---- Phase C: lookback — wave c sums predecessors' channel-c aggregates.
    double vA = 0.0, vW = 0.0;
    for (int p = lane; p < b; p += 64) {
        vA += agg_wait(&agg[(p * NCH + c) * 2 + 0]);
        vW += agg_wait(&agg[(p * NCH + c) * 2 + 1]);
    }
#pragma unroll
    for (int off = 32; off > 0; off >>= 1) {
        vA += __shfl_down(vA, off, 64);
        vW += __shfl_down(vW, off, 64);
    }
    double accA = __shfl(vA, 0, 64);
    double accW = __shfl(vW, 0, 64);

    const double dt  = (double)0.1f;   // match float32(0.1) bit pattern
    const double dt2 = dt * dt;
    const double p0  = (double)x[c];
    const double v0  = (double)x[NCH + c];

    // ---- Phase D: in-chunk scan, 4 sequential 64-step wave-scans.
#pragma unroll
    for (int k = 0; k < CHUNK / 64; ++k) {
        const int   tl = k * 64 + lane;
        const int   t  = b * CHUNK + tl;
        const float a  = sIn[tl * NCH + c];
        double iA = (double)a;
        double iW = (double)t * (double)a;
#pragma unroll
        for (int off = 1; off < 64; off <<= 1) {
            const double uA = __shfl_up(iA, off, 64);
            const double uW = __shfl_up(iW, off, 64);
            if (lane >= off) { iA += uA; iW += uW; }
        }
        const double runA = accA + iA;
        const double runW = accW + iW;
        const double vel = v0 + dt * runA;
        const double pos = p0 + dt * (double)(t + 1) * v0
                         + dt2 * (((double)t + 0.5) * runA - runW);
        sOut[tl * STATE + c]       = (float)pos;
        sOut[tl * STATE + NCH + c] = (float)vel;
        accA += __shfl(iA, 63, 64);
        accW += __shfl(iW, 63, 64);
    }
    __syncthreads();

    // ---- Phase E: coalesced writeout of the CHUNK x 12 state chunk.
    const float4* so4 = (const float4*)sOut;
    out4[b * (CHUNK * STATE / 4) + tid]       = so4[tid];
    out4[b * (CHUNK * STATE / 4) + BLK + tid] = so4[BLK + tid];
}

extern "C" void kernel_launch(void* const* d_in, const int* in_sizes, int n_in,
                              void* d_out, int out_size, void* d_ws, size_t ws_size,
                              hipStream_t stream) {
    const float* x       = (const float*)d_in[0];   // 12 floats: pos(6), vel(6)
    const float* actions = (const float*)d_in[1];   // [65536, 6]
    float*       out     = (float*)d_out;           // states(786432) + actions(393216)
    unsigned long long* agg = (unsigned long long*)d_ws;   // NB*NCH*2 u64 = 24 KiB

    hipLaunchKernelGGL(k_one, dim3(NB), dim3(BLK), 0, stream,
                       (const float4*)actions, x, agg, (float4*)out);
}